// Round 8
// baseline (7806.508 us; speedup 1.0000x reference)
//
#include <hip/hip_runtime.h>
#include <math.h>

#define BB 64
#define TT 512
#define II 64
#define HH 512
#define NBLK 192

typedef __attribute__((ext_vector_type(8))) short bf16x8;
typedef __attribute__((ext_vector_type(16))) float f32x16;

__device__ __forceinline__ float sigmoidf_(float x) {
    return 1.0f / (1.0f + expf(-x));
}

__device__ __forceinline__ unsigned short f2bf(float f) {
    union { float f; unsigned u; } v; v.f = f;
    unsigned r = v.u + 0x7fffu + ((v.u >> 16) & 1u);   // RTNE
    return (unsigned short)(r >> 16);
}
__device__ __forceinline__ float bf2f(unsigned short s) {
    union { unsigned u; float f; } v; v.u = ((unsigned)s) << 16;
    return v.f;
}

// --- fence-free coherent primitives (agent scope; compiler-tracked vmcnt) ---
__device__ __forceinline__ bf16x8 load16_byp(const void* p) {
    union { unsigned long long u[2]; bf16x8 v; } r;
    r.u[0] = __hip_atomic_load((const unsigned long long*)p, __ATOMIC_RELAXED, __HIP_MEMORY_SCOPE_AGENT);
    r.u[1] = __hip_atomic_load((const unsigned long long*)((const char*)p + 8), __ATOMIC_RELAXED, __HIP_MEMORY_SCOPE_AGENT);
    return r.v;
}
__device__ __forceinline__ void store8_thru(void* p, unsigned long long u) {
    __hip_atomic_store((unsigned long long*)p, u, __ATOMIC_RELAXED, __HIP_MEMORY_SCOPE_AGENT);
}
__device__ __forceinline__ void storef_thru(float* p, float v) {
    __hip_atomic_store(p, v, __ATOMIC_RELAXED, __HIP_MEMORY_SCOPE_AGENT);
}
__device__ __forceinline__ float loadf_byp(const float* p) {
    return __hip_atomic_load(p, __ATOMIC_RELAXED, __HIP_MEMORY_SCOPE_AGENT);
}
__device__ __forceinline__ void storeu_thru(unsigned* p, unsigned v) {
    __hip_atomic_store(p, v, __ATOMIC_RELAXED, __HIP_MEMORY_SCOPE_AGENT);
}

// Wave-parallel flag poll: lane i watches producer i's flag. No RMW anywhere.
__device__ __forceinline__ void poll_flags_ge(const unsigned* flags, unsigned tgt) {
    const int lane = threadIdx.x & 63;
    unsigned f = __hip_atomic_load(flags + lane, __ATOMIC_RELAXED, __HIP_MEMORY_SCOPE_AGENT);
    while (__ballot(f < tgt) != 0ull) {
        __builtin_amdgcn_s_sleep(1);
        f = __hip_atomic_load(flags + lane, __ATOMIC_RELAXED, __HIP_MEMORY_SCOPE_AGENT);
    }
}

// x [B,T,I] -> xTq [t][grp][b][hi 16B | lo 16B], grp = i>>3
__global__ __launch_bounds__(256) void pack_x(const float* __restrict__ x,
                                              char* __restrict__ xTq) {
    const int t = blockIdx.x;
    const int b = threadIdx.x & 63;
    const int gq = threadIdx.x >> 6;
    #pragma unroll
    for (int gi = 0; gi < 2; ++gi) {
        const int g2 = gq + gi * 4;
        const float* src = x + ((size_t)b * TT + t) * II + g2 * 8;
        float w[8];
        *(float4*)&w[0] = *(const float4*)src;
        *(float4*)&w[4] = *(const float4*)(src + 4);
        bf16x8 hv, lv;
        #pragma unroll
        for (int j = 0; j < 8; ++j) {
            unsigned short h = f2bf(w[j]);
            hv[j] = (short)h;
            lv[j] = (short)f2bf(w[j] - bf2f(h));
        }
        char* dst = xTq + (((size_t)t * 8 + g2) * 64 + b) * 32;
        *(bf16x8*)dst = hv;
        *(bf16x8*)(dst + 16) = lv;
    }
}

// ---- software-pipelined B-panel ----
template<int S0, int S1, int XEND, int SH>
__device__ __forceinline__ void stage(const char* __restrict__ xq, const char* __restrict__ rb,
                                      bf16x8* __restrict__ bh, bf16x8* __restrict__ bl) {
    #pragma unroll
    for (int s = S0; s < S1; ++s) {
        if (s < XEND) {
            bh[s - S0] = *(const bf16x8*)(xq + (size_t)s * 4096);
            bl[s - S0] = *(const bf16x8*)(xq + (size_t)s * 4096 + 16);
        } else {
            bh[s - S0] = load16_byp(rb + (size_t)(s - SH) * 4096);
            bl[s - S0] = load16_byp(rb + (size_t)(s - SH) * 4096 + 16);
        }
    }
    __builtin_amdgcn_sched_barrier(0);
}

template<int S0, int S1, int NA>
__device__ __forceinline__ void consume(const char* __restrict__ wa_h, const char* __restrict__ wa_l,
                                        bf16x8 (&bh)[NA], bf16x8 (&bl)[NA],
                                        f32x16& c0, f32x16& c1, f32x16& c2) {
    #pragma unroll
    for (int s = S0; s < S1; ++s) {
        bf16x8 ahi = *(const bf16x8*)(wa_h + (size_t)s * 2048);
        bf16x8 alo = *(const bf16x8*)(wa_l + (size_t)s * 2048);
        c0 = __builtin_amdgcn_mfma_f32_32x32x16_bf16(ahi, bh[s - S0], c0, 0, 0, 0);
        c1 = __builtin_amdgcn_mfma_f32_32x32x16_bf16(ahi, bl[s - S0], c1, 0, 0, 0);
        c2 = __builtin_amdgcn_mfma_f32_32x32x16_bf16(alo, bh[s - S0], c2, 0, 0, 0);
    }
}

template<int A, int B, int S1, int XEND, int SH, int PH, int NA>
__device__ __forceinline__ void pipe_next(const char* __restrict__ xq, const char* __restrict__ rb,
                                          const char* __restrict__ wa_h, const char* __restrict__ wa_l,
                                          bf16x8 (&bh)[NA], bf16x8 (&bl)[NA],
                                          f32x16& c0, f32x16& c1, f32x16& c2) {
    if constexpr (B >= S1) {
        consume<A, B>(wa_h, wa_l, bh, bl, c0, c1, c2);
    } else {
        constexpr int N2 = (S1 - B) < PH ? (S1 - B) : PH;
        bf16x8 bh2[N2], bl2[N2];
        stage<B, B + N2, XEND, SH>(xq, rb, bh2, bl2);
        consume<A, B>(wa_h, wa_l, bh, bl, c0, c1, c2);
        pipe_next<B, B + N2, S1, XEND, SH, PH>(xq, rb, wa_h, wa_l, bh2, bl2, c0, c1, c2);
    }
}

template<int S0, int S1, int XEND, int SH, int PH>
__device__ __forceinline__ void pipe(const char* __restrict__ xq, const char* __restrict__ rb,
                                     const char* __restrict__ wa_h, const char* __restrict__ wa_l,
                                     f32x16& c0, f32x16& c1, f32x16& c2) {
    constexpr int N1 = (S1 - S0) < PH ? (S1 - S0) : PH;
    bf16x8 bh[N1], bl[N1];
    stage<S0, S0 + N1, XEND, SH>(xq, rb, bh, bl);
    pipe_next<S0, S0 + N1, S1, XEND, SH, PH>(xq, rb, wa_h, wa_l, bh, bl, c0, c1, c2);
}

// Pack 32 gate-rows into LDS in MFMA A-fragment order, XOR-swizzled:
// byte = s*2048 + ((lane*32 + half*16) ^ (((lane>>2)&7)<<4))  — bijective per
// 2048B group; spreads the 64-lane ds_read_b128 uniformly over bank columns.
template<int IN_DIM, int NKS>
__device__ void pack_weights(const float* __restrict__ Wih, const float* __restrict__ Whh,
                             int hbase, char* __restrict__ WAc) {
    const int lane = threadIdx.x & 63;
    const int wq = threadIdx.x >> 6;
    const int m = lane & 31;
    const int lg = lane >> 5;
    const int swz = (lane & 28) << 2;
    const int off_h = (lane * 32) ^ swz;
    const int off_l = (lane * 32 + 16) ^ swz;
    const int grow = (m >> 3) * HH + hbase + (m & 7);
    const float* wi = Wih + (size_t)grow * IN_DIM;
    const float* wh = Whh + (size_t)grow * HH;
    for (int s = wq; s < NKS; s += 4) {
        const int k8 = s * 16 + lg * 8;
        const float* src = (k8 < IN_DIM) ? (wi + k8) : (wh + (k8 - IN_DIM));
        float w[8];
        *(float4*)&w[0] = *(const float4*)src;
        *(float4*)&w[4] = *(const float4*)(src + 4);
        bf16x8 hv, lv;
        #pragma unroll
        for (int j = 0; j < 8; ++j) {
            unsigned short h = f2bf(w[j]);
            hv[j] = (short)h;
            lv[j] = (short)f2bf(w[j] - bf2f(h));
        }
        char* dst = WAc + (size_t)s * 2048;
        *(bf16x8*)(dst + off_h) = hv;
        *(bf16x8*)(dst + off_l) = lv;
    }
}

// Dataflow sync: flags[l*64 + tile] = completed steps of that block (monotonic,
// zeroed by the launch-start memset). No counting barrier, no atomics RMW.
template<int LAYER, int IN_DIM, int NKS, int KH, int SH>
__device__ void lstm_core(int tile,
                          const char* __restrict__ xsrc, char* __restrict__ xdst,
                          char* __restrict__ hbuf,
                          float* __restrict__ h2last, unsigned* __restrict__ flags,
                          const float* __restrict__ Wih, const float* __restrict__ Whh,
                          const float* __restrict__ bih, const float* __restrict__ bhh,
                          char* __restrict__ WAc, float* __restrict__ redbuf) {
    const int tid = threadIdx.x;
    const int lane = tid & 63;
    const int wq = tid >> 6;
    const int ntile = wq & 1;
    const int khalf = wq >> 1;
    const int lg = lane >> 5;
    const int b = ntile * 32 + (lane & 31);
    const int hbase = tile * 8;

    pack_weights<IN_DIM, NKS>(Wih, Whh, hbase, WAc);

    float bias_v[16];
    float cst[4] = {0.f, 0.f, 0.f, 0.f};
    if (khalf == 0) {
        #pragma unroll
        for (int g = 0; g < 4; ++g)
            #pragma unroll
            for (int j = 0; j < 4; ++j) {
                const int grow = g * HH + hbase + j + 4 * lg;
                bias_v[g * 4 + j] = bih[grow] + bhh[grow];
            }
    }
    __syncthreads();   // WA ready

    const int swz = (lane & 28) << 2;
    const char* wa_h = WAc + ((lane * 32) ^ swz);
    const char* wa_l = WAc + ((lane * 32 + 16) ^ swz);
    unsigned* const own  = flags + LAYER * 64;
    unsigned* const prev = own - 64;   // valid only for LAYER>0
    unsigned* const next = own + 64;   // valid only for LAYER<2
    const int xoff = lg * 2048 + b * 32;

    for (int t = 0; t < TT; ++t) {
        f32x16 c0 = {0,0,0,0,0,0,0,0,0,0,0,0,0,0,0,0};
        f32x16 c1 = c0, c2 = c0;
        const char* rb = hbuf + (size_t)(t & 1) * 131072 + xoff;   // h(t-1) parity

        if (khalf == 0) {
            if (LAYER == 0) {
                if (t > 0) poll_flags_ge(own, (unsigned)t);        // h(t-1) ready
                const char* xq = xsrc + (size_t)t * 16384 + xoff;
                if (t > 0) pipe<0, KH, 4, SH, 8>(xq, rb, wa_h, wa_l, c0, c1, c2);
                else       pipe<0, 4, 4, SH, 8>(xq, rb, wa_h, wa_l, c0, c1, c2);
            } else {
                poll_flags_ge(prev, (unsigned)(t + 1));            // x(t) ready
                const char* xb = xsrc + (size_t)(t % 3) * 131072 + xoff;
                pipe<0, KH, 0, 0, 8>(nullptr, xb, wa_h, wa_l, c0, c1, c2);
            }
        } else {
            if (t > 0) {
                poll_flags_ge(own, (unsigned)t);                   // h(t-1) ready
                pipe<KH, NKS, 0, SH, 8>(nullptr, rb, wa_h, wa_l, c0, c1, c2);
            }
        }

        f32x16 cs = c0 + c1 + c2;

        if (khalf == 1) {
            float* pw = &redbuf[((size_t)ntile * 64 + lane) * 20];
            #pragma unroll
            for (int q = 0; q < 4; ++q) {
                float4 v; v.x = cs[q*4+0]; v.y = cs[q*4+1]; v.z = cs[q*4+2]; v.w = cs[q*4+3];
                *(float4*)(pw + q * 4) = v;
            }
        }
        __syncthreads();
        if (khalf == 0) {
            const float* pr = &redbuf[((size_t)ntile * 64 + lane) * 20];
            float gate[16];
            #pragma unroll
            for (int r = 0; r < 16; ++r) gate[r] = cs[r] + pr[r] + bias_v[r];

            unsigned short his[4], los[4];
            #pragma unroll
            for (int j = 0; j < 4; ++j) {
                const float iv = sigmoidf_(gate[0 + j]);
                const float fv = sigmoidf_(gate[4 + j]);
                const float gv = tanhf(gate[8 + j]);
                const float ov = sigmoidf_(gate[12 + j]);
                cst[j] = fv * cst[j] + iv * gv;
                const float hv = ov * tanhf(cst[j]);
                his[j] = f2bf(hv);
                los[j] = f2bf(hv - bf2f(his[j]));
                if (LAYER == 2 && t == TT - 1)
                    storef_thru(h2last + (size_t)(hbase + j + 4 * lg) * 64 + b, hv);
            }
            unsigned long long hi2 = (unsigned long long)((unsigned)his[0] | ((unsigned)his[1] << 16))
                                   | ((unsigned long long)((unsigned)his[2] | ((unsigned)his[3] << 16)) << 32);
            unsigned long long lo2 = (unsigned long long)((unsigned)los[0] | ((unsigned)los[1] << 16))
                                   | ((unsigned long long)((unsigned)los[2] | ((unsigned)los[3] << 16)) << 32);

            // own-layer h(t) -> parity (t+1)&1 (safe: own flags >= t observed
            // by khalf1 before the redbuf __syncthreads => nobody reads h(t-2))
            char* d2 = hbuf + (size_t)((t + 1) & 1) * 131072 + (size_t)tile * 2048 + b * 32 + lg * 8;
            store8_thru(d2, hi2);
            store8_thru(d2 + 16, lo2);
            if (LAYER < 2) {
                // x-slot reuse guard (lagging ~always satisfied)
                if (t >= 3) poll_flags_ge(next, (unsigned)(t - 2));
                char* d1 = xdst + (size_t)(t % 3) * 131072 + (size_t)tile * 2048 + b * 32 + lg * 8;
                store8_thru(d1, hi2);
                store8_thru(d1 + 16, lo2);
            }
        }
        // publish: all stores drained (per wave), then one flag store
        __builtin_amdgcn_s_waitcnt(0);
        __syncthreads();
        if (tid == 0) storeu_thru(own + tile, (unsigned)(t + 1));
    }
}

__global__ __launch_bounds__(256, 1) void lstm_wavefront(
    const char* __restrict__ xTq,
    char* __restrict__ xbuf1, char* __restrict__ xbuf2,
    char* __restrict__ hbuf0, char* __restrict__ hbuf1, char* __restrict__ hbuf2,
    float* __restrict__ h2last, unsigned* __restrict__ flags,
    const float* __restrict__ Wih0, const float* __restrict__ Whh0,
    const float* __restrict__ bih0, const float* __restrict__ bhh0,
    const float* __restrict__ Wih1, const float* __restrict__ Whh1,
    const float* __restrict__ bih1, const float* __restrict__ bhh1,
    const float* __restrict__ Wih2, const float* __restrict__ Whh2,
    const float* __restrict__ bih2, const float* __restrict__ bhh2,
    const float* __restrict__ fcw, const float* __restrict__ fcb,
    float* __restrict__ out) {

    __shared__ short WA[64 * 64 * 16];     // 128 KB
    __shared__ float redbuf[2 * 64 * 20];  // 10 KB
    __shared__ float fcred[256];

    const int l = blockIdx.x >> 6;
    const int tile = blockIdx.x & 63;
    char* WAc = (char*)WA;

    if (l == 0)
        lstm_core<0, II, 36, 18, 4>(tile, xTq, xbuf1, hbuf0, h2last, flags,
                                    Wih0, Whh0, bih0, bhh0, WAc, redbuf);
    else if (l == 1)
        lstm_core<1, HH, 64, 32, 32>(tile, xbuf1, xbuf2, hbuf1, h2last, flags,
                                     Wih1, Whh1, bih1, bhh1, WAc, redbuf);
    else
        lstm_core<2, HH, 64, 32, 32>(tile, xbuf2, nullptr, hbuf2, h2last, flags,
                                     Wih2, Whh2, bih2, bhh2, WAc, redbuf);

    // final FC on h2[T-1]
    if (blockIdx.x == 0) {
        poll_flags_ge(flags + 2 * 64, (unsigned)TT);
        const int tid = threadIdx.x;
        const int b = tid & 63, kq = tid >> 6;
        float s = 0.f;
        const float* hp = h2last + (size_t)kq * 128 * 64 + b;
        const float* wp = fcw + kq * 128;
        #pragma unroll 8
        for (int k = 0; k < 128; ++k)
            s = fmaf(loadf_byp(hp + (size_t)k * 64), wp[k], s);
        fcred[tid] = s;
        __syncthreads();
        if (tid < 64)
            out[tid] = fcred[tid] + fcred[64 + tid] + fcred[128 + tid] + fcred[192 + tid] + fcb[0];
    }
}

extern "C" void kernel_launch(void* const* d_in, const int* in_sizes, int n_in,
                              void* d_out, int out_size, void* d_ws, size_t ws_size,
                              hipStream_t stream) {
    (void)in_sizes; (void)n_in; (void)out_size; (void)ws_size;

    const float* x    = (const float*)d_in[0];
    const float* Wih0 = (const float*)d_in[1];
    const float* Whh0 = (const float*)d_in[2];
    const float* bih0 = (const float*)d_in[3];
    const float* bhh0 = (const float*)d_in[4];
    const float* Wih1 = (const float*)d_in[5];
    const float* Whh1 = (const float*)d_in[6];
    const float* bih1 = (const float*)d_in[7];
    const float* bhh1 = (const float*)d_in[8];
    const float* Wih2 = (const float*)d_in[9];
    const float* Whh2 = (const float*)d_in[10];
    const float* bih2 = (const float*)d_in[11];
    const float* bhh2 = (const float*)d_in[12];
    const float* fcw  = (const float*)d_in[13];
    const float* fcb  = (const float*)d_in[14];

    char* ws = (char*)d_ws;
    unsigned* flags = (unsigned*)ws;               // 4 KB (3*64 flags)
    char* xbuf1   = ws + 4096;                     // 3*64*64*32 = 384 KB
    char* xbuf2   = xbuf1 + 3 * 64 * 64 * 32;
    char* hbuf0   = xbuf2 + 3 * 64 * 64 * 32;      // 2*64*64*32 = 256 KB each
    char* hbuf1   = hbuf0 + 2 * 64 * 64 * 32;
    char* hbuf2   = hbuf1 + 2 * 64 * 64 * 32;
    float* h2last = (float*)(hbuf2 + 2 * 64 * 64 * 32);   // 128 KB
    char* xTq     = (char*)h2last + 512 * 64 * 4;  // 8 MB

    hipMemsetAsync(flags, 0, 4096, stream);

    pack_x<<<TT, 256, 0, stream>>>(x, xTq);

    lstm_wavefront<<<NBLK, 256, 0, stream>>>(
        xTq, xbuf1, xbuf2, hbuf0, hbuf1, hbuf2, h2last, flags,
        Wih0, Whh0, bih0, bhh0,
        Wih1, Whh1, bih1, bhh1,
        Wih2, Whh2, bih2, bhh2,
        fcw, fcb, (float*)d_out);
}

// Round 9
// 5986.914 us; speedup vs baseline: 1.3039x; 1.3039x over previous
//
#include <hip/hip_runtime.h>
#include <math.h>

#define BB 64
#define TT 512
#define II 64
#define HH 512
#define NCOMP 192
#define NBLK 195   // 192 compute + 3 monitor blocks

typedef __attribute__((ext_vector_type(8))) short bf16x8;
typedef __attribute__((ext_vector_type(16))) float f32x16;

__device__ __forceinline__ float sigmoidf_(float x) {
    return 1.0f / (1.0f + expf(-x));
}

__device__ __forceinline__ unsigned short f2bf(float f) {
    union { float f; unsigned u; } v; v.f = f;
    unsigned r = v.u + 0x7fffu + ((v.u >> 16) & 1u);   // RTNE
    return (unsigned short)(r >> 16);
}
__device__ __forceinline__ float bf2f(unsigned short s) {
    union { unsigned u; float f; } v; v.u = ((unsigned)s) << 16;
    return v.f;
}

// --- fence-free coherent primitives (agent scope; compiler-tracked vmcnt) ---
__device__ __forceinline__ bf16x8 load16_byp(const void* p) {
    union { unsigned long long u[2]; bf16x8 v; } r;
    r.u[0] = __hip_atomic_load((const unsigned long long*)p, __ATOMIC_RELAXED, __HIP_MEMORY_SCOPE_AGENT);
    r.u[1] = __hip_atomic_load((const unsigned long long*)((const char*)p + 8), __ATOMIC_RELAXED, __HIP_MEMORY_SCOPE_AGENT);
    return r.v;
}
__device__ __forceinline__ void store8_thru(void* p, unsigned long long u) {
    __hip_atomic_store((unsigned long long*)p, u, __ATOMIC_RELAXED, __HIP_MEMORY_SCOPE_AGENT);
}
__device__ __forceinline__ void storef_thru(float* p, float v) {
    __hip_atomic_store(p, v, __ATOMIC_RELAXED, __HIP_MEMORY_SCOPE_AGENT);
}
__device__ __forceinline__ float loadf_byp(const float* p) {
    return __hip_atomic_load(p, __ATOMIC_RELAXED, __HIP_MEMORY_SCOPE_AGENT);
}
__device__ __forceinline__ void storeu_thru(unsigned* p, unsigned v) {
    __hip_atomic_store(p, v, __ATOMIC_RELAXED, __HIP_MEMORY_SCOPE_AGENT);
}
__device__ __forceinline__ unsigned loadu_byp(const unsigned* p) {
    return __hip_atomic_load(p, __ATOMIC_RELAXED, __HIP_MEMORY_SCOPE_AGENT);
}

// Flag arrays: one word per (layer,tile), spread at 128B (32-dword) stride so no
// two flags share a cacheline. arrive[] written by compute blocks (1 writer each,
// 1 reader: the monitor). release[] written by monitors (1 writer each, <=3
// readers: own tile + neighbors' same-tile polls). Zero RMW anywhere.
#define FLAG_STRIDE 32   // dwords = 128 B

// Monitor block (one per layer): waits for all 64 arrivals >= g, then fans the
// release out to 64 private words. Release-after-observation gives transitive
// visibility: producer drained data before arrive; monitor saw arrive; so any
// consumer that sees release sees the data at L3.
__device__ void monitor_loop(unsigned* arr, unsigned* rel) {
    const int lane = threadIdx.x & 63;
    unsigned* a = arr + (size_t)lane * FLAG_STRIDE;
    unsigned* r = rel + (size_t)lane * FLAG_STRIDE;
    for (unsigned g = 1; g <= TT; ++g) {
        unsigned f = loadu_byp(a);
        while (__ballot(f < g) != 0ull) {
            __builtin_amdgcn_s_sleep(1);
            f = loadu_byp(a);
        }
        storeu_thru(r, g);
    }
}

// Compute-block step gate (wave 0 only): lane 0 polls own release >= t,
// lane 1 polls prev-layer release >= t+1 (x(t) ready), lane 2 polls next-layer
// release >= t-2 (x-slot reuse). One ballot loop covers all conditions.
template<int LAYER>
__device__ __forceinline__ void step_gate(const unsigned* rel_own, const unsigned* rel_prev,
                                          const unsigned* rel_next, int t) {
    const int lane = threadIdx.x & 63;
    const unsigned* addr = rel_own;
    unsigned tgt = (unsigned)t;
    if (LAYER > 0 && lane == 1) { addr = rel_prev; tgt = (unsigned)(t + 1); }
    if (LAYER < 2 && lane == 2) { addr = rel_next; tgt = (t >= 3) ? (unsigned)(t - 2) : 0u; }
    unsigned f = loadu_byp(addr);
    while (__ballot(f < tgt) != 0ull) {
        __builtin_amdgcn_s_sleep(1);
        f = loadu_byp(addr);
    }
}

// x [B,T,I] -> xTq [t][grp][b][hi 16B | lo 16B], grp = i>>3
__global__ __launch_bounds__(256) void pack_x(const float* __restrict__ x,
                                              char* __restrict__ xTq) {
    const int t = blockIdx.x;
    const int b = threadIdx.x & 63;
    const int gq = threadIdx.x >> 6;
    #pragma unroll
    for (int gi = 0; gi < 2; ++gi) {
        const int g2 = gq + gi * 4;
        const float* src = x + ((size_t)b * TT + t) * II + g2 * 8;
        float w[8];
        *(float4*)&w[0] = *(const float4*)src;
        *(float4*)&w[4] = *(const float4*)(src + 4);
        bf16x8 hv, lv;
        #pragma unroll
        for (int j = 0; j < 8; ++j) {
            unsigned short h = f2bf(w[j]);
            hv[j] = (short)h;
            lv[j] = (short)f2bf(w[j] - bf2f(h));
        }
        char* dst = xTq + (((size_t)t * 8 + g2) * 64 + b) * 32;
        *(bf16x8*)dst = hv;
        *(bf16x8*)(dst + 16) = lv;
    }
}

// ---- software-pipelined B-panel ----
template<int S0, int S1, int XEND, int SH>
__device__ __forceinline__ void stage(const char* __restrict__ xq, const char* __restrict__ rb,
                                      bf16x8* __restrict__ bh, bf16x8* __restrict__ bl) {
    #pragma unroll
    for (int s = S0; s < S1; ++s) {
        if (s < XEND) {
            bh[s - S0] = *(const bf16x8*)(xq + (size_t)s * 4096);
            bl[s - S0] = *(const bf16x8*)(xq + (size_t)s * 4096 + 16);
        } else {
            bh[s - S0] = load16_byp(rb + (size_t)(s - SH) * 4096);
            bl[s - S0] = load16_byp(rb + (size_t)(s - SH) * 4096 + 16);
        }
    }
    __builtin_amdgcn_sched_barrier(0);
}

template<int S0, int S1, int NA>
__device__ __forceinline__ void consume(const char* __restrict__ wa_h, const char* __restrict__ wa_l,
                                        bf16x8 (&bh)[NA], bf16x8 (&bl)[NA],
                                        f32x16& c0, f32x16& c1, f32x16& c2) {
    #pragma unroll
    for (int s = S0; s < S1; ++s) {
        bf16x8 ahi = *(const bf16x8*)(wa_h + (size_t)s * 2048);
        bf16x8 alo = *(const bf16x8*)(wa_l + (size_t)s * 2048);
        c0 = __builtin_amdgcn_mfma_f32_32x32x16_bf16(ahi, bh[s - S0], c0, 0, 0, 0);
        c1 = __builtin_amdgcn_mfma_f32_32x32x16_bf16(ahi, bl[s - S0], c1, 0, 0, 0);
        c2 = __builtin_amdgcn_mfma_f32_32x32x16_bf16(alo, bh[s - S0], c2, 0, 0, 0);
    }
}

template<int A, int B, int S1, int XEND, int SH, int PH, int NA>
__device__ __forceinline__ void pipe_next(const char* __restrict__ xq, const char* __restrict__ rb,
                                          const char* __restrict__ wa_h, const char* __restrict__ wa_l,
                                          bf16x8 (&bh)[NA], bf16x8 (&bl)[NA],
                                          f32x16& c0, f32x16& c1, f32x16& c2) {
    if constexpr (B >= S1) {
        consume<A, B>(wa_h, wa_l, bh, bl, c0, c1, c2);
    } else {
        constexpr int N2 = (S1 - B) < PH ? (S1 - B) : PH;
        bf16x8 bh2[N2], bl2[N2];
        stage<B, B + N2, XEND, SH>(xq, rb, bh2, bl2);
        consume<A, B>(wa_h, wa_l, bh, bl, c0, c1, c2);
        pipe_next<B, B + N2, S1, XEND, SH, PH>(xq, rb, wa_h, wa_l, bh2, bl2, c0, c1, c2);
    }
}

template<int S0, int S1, int XEND, int SH, int PH>
__device__ __forceinline__ void pipe(const char* __restrict__ xq, const char* __restrict__ rb,
                                     const char* __restrict__ wa_h, const char* __restrict__ wa_l,
                                     f32x16& c0, f32x16& c1, f32x16& c2) {
    constexpr int N1 = (S1 - S0) < PH ? (S1 - S0) : PH;
    bf16x8 bh[N1], bl[N1];
    stage<S0, S0 + N1, XEND, SH>(xq, rb, bh, bl);
    pipe_next<S0, S0 + N1, S1, XEND, SH, PH>(xq, rb, wa_h, wa_l, bh, bl, c0, c1, c2);
}

// Pack 32 gate-rows into LDS in MFMA A-fragment order (XOR-swizzled layout).
template<int IN_DIM, int NKS>
__device__ void pack_weights(const float* __restrict__ Wih, const float* __restrict__ Whh,
                             int hbase, char* __restrict__ WAc) {
    const int lane = threadIdx.x & 63;
    const int wq = threadIdx.x >> 6;
    const int m = lane & 31;
    const int lg = lane >> 5;
    const int swz = (lane & 28) << 2;
    const int off_h = (lane * 32) ^ swz;
    const int off_l = (lane * 32 + 16) ^ swz;
    const int grow = (m >> 3) * HH + hbase + (m & 7);
    const float* wi = Wih + (size_t)grow * IN_DIM;
    const float* wh = Whh + (size_t)grow * HH;
    for (int s = wq; s < NKS; s += 4) {
        const int k8 = s * 16 + lg * 8;
        const float* src = (k8 < IN_DIM) ? (wi + k8) : (wh + (k8 - IN_DIM));
        float w[8];
        *(float4*)&w[0] = *(const float4*)src;
        *(float4*)&w[4] = *(const float4*)(src + 4);
        bf16x8 hv, lv;
        #pragma unroll
        for (int j = 0; j < 8; ++j) {
            unsigned short h = f2bf(w[j]);
            hv[j] = (short)h;
            lv[j] = (short)f2bf(w[j] - bf2f(h));
        }
        char* dst = WAc + (size_t)s * 2048;
        *(bf16x8*)(dst + off_h) = hv;
        *(bf16x8*)(dst + off_l) = lv;
    }
}

template<int LAYER, int IN_DIM, int NKS, int KH, int SH>
__device__ void lstm_core(int tile,
                          const char* __restrict__ xsrc, char* __restrict__ xdst,
                          char* __restrict__ hbuf,
                          float* __restrict__ h2last,
                          unsigned* __restrict__ arrive, unsigned* __restrict__ release,
                          const float* __restrict__ Wih, const float* __restrict__ Whh,
                          const float* __restrict__ bih, const float* __restrict__ bhh,
                          char* __restrict__ WAc, float* __restrict__ redbuf) {
    const int tid = threadIdx.x;
    const int lane = tid & 63;
    const int wq = tid >> 6;
    const int ntile = wq & 1;
    const int khalf = wq >> 1;
    const int lg = lane >> 5;
    const int b = ntile * 32 + (lane & 31);
    const int hbase = tile * 8;

    pack_weights<IN_DIM, NKS>(Wih, Whh, hbase, WAc);

    float bias_v[16];
    float cst[4] = {0.f, 0.f, 0.f, 0.f};
    if (khalf == 0) {
        #pragma unroll
        for (int g = 0; g < 4; ++g)
            #pragma unroll
            for (int j = 0; j < 4; ++j) {
                const int grow = g * HH + hbase + j + 4 * lg;
                bias_v[g * 4 + j] = bih[grow] + bhh[grow];
            }
    }
    __syncthreads();   // WA ready

    const int swz = (lane & 28) << 2;
    const char* wa_h = WAc + ((lane * 32) ^ swz);
    const char* wa_l = WAc + ((lane * 32 + 16) ^ swz);

    unsigned* const arr_own  = arrive + (size_t)(LAYER * 64 + tile) * FLAG_STRIDE;
    const unsigned* rel_own  = release + (size_t)(LAYER * 64 + tile) * FLAG_STRIDE;
    const unsigned* rel_prev = (LAYER > 0) ? release + (size_t)((LAYER - 1) * 64 + tile) * FLAG_STRIDE : rel_own;
    const unsigned* rel_next = (LAYER < 2) ? release + (size_t)((LAYER + 1) * 64 + tile) * FLAG_STRIDE : rel_own;
    const int xoff = lg * 2048 + b * 32;

    for (int t = 0; t < TT; ++t) {
        if (tid < 64) step_gate<LAYER>(rel_own, rel_prev, rel_next, t);
        __syncthreads();   // gate open for all waves

        f32x16 c0 = {0,0,0,0,0,0,0,0,0,0,0,0,0,0,0,0};
        f32x16 c1 = c0, c2 = c0;
        const char* rb = hbuf + (size_t)(t & 1) * 131072 + xoff;   // h(t-1) parity

        if (khalf == 0) {
            if (LAYER == 0) {
                const char* xq = xsrc + (size_t)t * 16384 + xoff;
                if (t > 0) pipe<0, KH, 4, SH, 8>(xq, rb, wa_h, wa_l, c0, c1, c2);
                else       pipe<0, 4, 4, SH, 8>(xq, rb, wa_h, wa_l, c0, c1, c2);
            } else {
                const char* xb = xsrc + (size_t)(t % 3) * 131072 + xoff;
                pipe<0, KH, 0, 0, 8>(nullptr, xb, wa_h, wa_l, c0, c1, c2);
            }
        } else {
            if (t > 0) pipe<KH, NKS, 0, SH, 8>(nullptr, rb, wa_h, wa_l, c0, c1, c2);
        }

        f32x16 cs = c0 + c1 + c2;

        if (khalf == 1) {
            float* pw = &redbuf[((size_t)ntile * 64 + lane) * 20];
            #pragma unroll
            for (int q = 0; q < 4; ++q) {
                float4 v; v.x = cs[q*4+0]; v.y = cs[q*4+1]; v.z = cs[q*4+2]; v.w = cs[q*4+3];
                *(float4*)(pw + q * 4) = v;
            }
        }
        __syncthreads();
        if (khalf == 0) {
            // read partials back as float4 (same quad pattern as the writes:
            // (lane*5)&7 — conflict-free; the old scalar reads were 8-way)
            const float* pr = &redbuf[((size_t)ntile * 64 + lane) * 20];
            float prv[16];
            #pragma unroll
            for (int q = 0; q < 4; ++q)
                *(float4*)&prv[q * 4] = *(const float4*)(pr + q * 4);
            float gate[16];
            #pragma unroll
            for (int r = 0; r < 16; ++r) gate[r] = cs[r] + prv[r] + bias_v[r];

            unsigned short his[4], los[4];
            #pragma unroll
            for (int j = 0; j < 4; ++j) {
                const float iv = sigmoidf_(gate[0 + j]);
                const float fv = sigmoidf_(gate[4 + j]);
                const float gv = tanhf(gate[8 + j]);
                const float ov = sigmoidf_(gate[12 + j]);
                cst[j] = fv * cst[j] + iv * gv;
                const float hv = ov * tanhf(cst[j]);
                his[j] = f2bf(hv);
                los[j] = f2bf(hv - bf2f(his[j]));
                if (LAYER == 2 && t == TT - 1)
                    storef_thru(h2last + (size_t)(hbase + j + 4 * lg) * 64 + b, hv);
            }
            unsigned long long hi2 = (unsigned long long)((unsigned)his[0] | ((unsigned)his[1] << 16))
                                   | ((unsigned long long)((unsigned)his[2] | ((unsigned)his[3] << 16)) << 32);
            unsigned long long lo2 = (unsigned long long)((unsigned)los[0] | ((unsigned)los[1] << 16))
                                   | ((unsigned long long)((unsigned)los[2] | ((unsigned)los[3] << 16)) << 32);

            char* d2 = hbuf + (size_t)((t + 1) & 1) * 131072 + (size_t)tile * 2048 + b * 32 + lg * 8;
            store8_thru(d2, hi2);
            store8_thru(d2 + 16, lo2);
            if (LAYER < 2) {
                char* d1 = xdst + (size_t)(t % 3) * 131072 + (size_t)tile * 2048 + b * 32 + lg * 8;
                store8_thru(d1, hi2);
                store8_thru(d1 + 16, lo2);
            }
        }
        // publish: every wave drains its own stores, then one arrive store
        __builtin_amdgcn_s_waitcnt(0);
        __syncthreads();
        if (tid == 0) storeu_thru(arr_own, (unsigned)(t + 1));
    }
}

__global__ __launch_bounds__(256, 1) void lstm_wavefront(
    const char* __restrict__ xTq,
    char* __restrict__ xbuf1, char* __restrict__ xbuf2,
    char* __restrict__ hbuf0, char* __restrict__ hbuf1, char* __restrict__ hbuf2,
    float* __restrict__ h2last,
    unsigned* __restrict__ arrive, unsigned* __restrict__ release,
    const float* __restrict__ Wih0, const float* __restrict__ Whh0,
    const float* __restrict__ bih0, const float* __restrict__ bhh0,
    const float* __restrict__ Wih1, const float* __restrict__ Whh1,
    const float* __restrict__ bih1, const float* __restrict__ bhh1,
    const float* __restrict__ Wih2, const float* __restrict__ Whh2,
    const float* __restrict__ bih2, const float* __restrict__ bhh2,
    const float* __restrict__ fcw, const float* __restrict__ fcb,
    float* __restrict__ out) {

    __shared__ short WA[64 * 64 * 16];     // 128 KB
    __shared__ float redbuf[2 * 64 * 20];  // 10 KB
    __shared__ float fcred[256];

    // Monitor blocks: one per layer, wave 0 only.
    if (blockIdx.x >= NCOMP) {
        const int l = blockIdx.x - NCOMP;
        if (threadIdx.x < 64)
            monitor_loop(arrive + (size_t)l * 64 * FLAG_STRIDE,
                         release + (size_t)l * 64 * FLAG_STRIDE);
        return;
    }

    const int l = blockIdx.x >> 6;
    const int tile = blockIdx.x & 63;
    char* WAc = (char*)WA;

    if (l == 0)
        lstm_core<0, II, 36, 18, 4>(tile, xTq, xbuf1, hbuf0, h2last, arrive, release,
                                    Wih0, Whh0, bih0, bhh0, WAc, redbuf);
    else if (l == 1)
        lstm_core<1, HH, 64, 32, 32>(tile, xbuf1, xbuf2, hbuf1, h2last, arrive, release,
                                     Wih1, Whh1, bih1, bhh1, WAc, redbuf);
    else
        lstm_core<2, HH, 64, 32, 32>(tile, xbuf2, nullptr, hbuf2, h2last, arrive, release,
                                     Wih2, Whh2, bih2, bhh2, WAc, redbuf);

    // final FC on h2[T-1]
    if (blockIdx.x == 0) {
        const unsigned* done = release + (size_t)(2 * 64) * FLAG_STRIDE;  // rel(2, tile 0)
        if (threadIdx.x < 64) {
            unsigned f = loadu_byp(done);
            while (__ballot(f < (unsigned)TT) != 0ull) {
                __builtin_amdgcn_s_sleep(1);
                f = loadu_byp(done);
            }
        }
        __syncthreads();
        const int tid = threadIdx.x;
        const int b = tid & 63, kq = tid >> 6;
        float s = 0.f;
        const float* hp = h2last + (size_t)kq * 128 * 64 + b;
        const float* wp = fcw + kq * 128;
        #pragma unroll 8
        for (int k = 0; k < 128; ++k)
            s = fmaf(loadf_byp(hp + (size_t)k * 64), wp[k], s);
        fcred[tid] = s;
        __syncthreads();
        if (tid < 64)
            out[tid] = fcred[tid] + fcred[64 + tid] + fcred[128 + tid] + fcred[192 + tid] + fcb[0];
    }
}

extern "C" void kernel_launch(void* const* d_in, const int* in_sizes, int n_in,
                              void* d_out, int out_size, void* d_ws, size_t ws_size,
                              hipStream_t stream) {
    (void)in_sizes; (void)n_in; (void)out_size; (void)ws_size;

    const float* x    = (const float*)d_in[0];
    const float* Wih0 = (const float*)d_in[1];
    const float* Whh0 = (const float*)d_in[2];
    const float* bih0 = (const float*)d_in[3];
    const float* bhh0 = (const float*)d_in[4];
    const float* Wih1 = (const float*)d_in[5];
    const float* Whh1 = (const float*)d_in[6];
    const float* bih1 = (const float*)d_in[7];
    const float* bhh1 = (const float*)d_in[8];
    const float* Wih2 = (const float*)d_in[9];
    const float* Whh2 = (const float*)d_in[10];
    const float* bih2 = (const float*)d_in[11];
    const float* bhh2 = (const float*)d_in[12];
    const float* fcw  = (const float*)d_in[13];
    const float* fcb  = (const float*)d_in[14];

    char* ws = (char*)d_ws;
    unsigned* arrive  = (unsigned*)ws;                     // 3*64*128B = 24 KB
    unsigned* release = (unsigned*)(ws + 24576);           // 24 KB
    char* xbuf1   = ws + 65536;                            // 3*64*64*32 = 384 KB
    char* xbuf2   = xbuf1 + 3 * 64 * 64 * 32;
    char* hbuf0   = xbuf2 + 3 * 64 * 64 * 32;              // 2*64*64*32 = 256 KB each
    char* hbuf1   = hbuf0 + 2 * 64 * 64 * 32;
    char* hbuf2   = hbuf1 + 2 * 64 * 64 * 32;
    float* h2last = (float*)(hbuf2 + 2 * 64 * 64 * 32);    // 128 KB
    char* xTq     = (char*)h2last + 512 * 64 * 4;          // 8 MB

    hipMemsetAsync(ws, 0, 65536, stream);

    pack_x<<<TT, 256, 0, stream>>>(x, xTq);

    lstm_wavefront<<<NBLK, 256, 0, stream>>>(
        xTq, xbuf1, xbuf2, hbuf0, hbuf1, hbuf2, h2last, arrive, release,
        Wih0, Whh0, bih0, bhh0,
        Wih1, Whh1, bih1, bhh1,
        Wih2, Whh2, bih2, bhh2,
        fcw, fcb, (float*)d_out);
}

// Round 10
// 3892.738 us; speedup vs baseline: 2.0054x; 1.5380x over previous
//
#include <hip/hip_runtime.h>
#include <math.h>

#define BB 64
#define TT 512
#define II 64
#define HH 512
#define NCOMP 192
#define NBLK 195   // 192 compute + 3 monitor blocks
#define FLAG_STRIDE 32

typedef __attribute__((ext_vector_type(8))) short bf16x8;
typedef __attribute__((ext_vector_type(16))) float f32x16;

__device__ __forceinline__ float sigmoidf_(float x) {
    return 1.0f / (1.0f + expf(-x));
}
__device__ __forceinline__ unsigned short f2bf(float f) {
    union { float f; unsigned u; } v; v.f = f;
    unsigned r = v.u + 0x7fffu + ((v.u >> 16) & 1u);   // RTNE
    return (unsigned short)(r >> 16);
}
__device__ __forceinline__ float bf2f(unsigned short s) {
    union { unsigned u; float f; } v; v.u = ((unsigned)s) << 16;
    return v.f;
}

// --- coherent scalar primitives (compiler-tracked) ---
__device__ __forceinline__ void store8_thru(void* p, unsigned long long u) {
    __hip_atomic_store((unsigned long long*)p, u, __ATOMIC_RELAXED, __HIP_MEMORY_SCOPE_AGENT);
}
__device__ __forceinline__ void storef_thru(float* p, float v) {
    __hip_atomic_store(p, v, __ATOMIC_RELAXED, __HIP_MEMORY_SCOPE_AGENT);
}
__device__ __forceinline__ float loadf_byp(const float* p) {
    return __hip_atomic_load(p, __ATOMIC_RELAXED, __HIP_MEMORY_SCOPE_AGENT);
}
__device__ __forceinline__ void storeu_thru(unsigned* p, unsigned v) {
    __hip_atomic_store(p, v, __ATOMIC_RELAXED, __HIP_MEMORY_SCOPE_AGENT);
}
__device__ __forceinline__ unsigned loadu_byp(const unsigned* p) {
    return __hip_atomic_load(p, __ATOMIC_RELAXED, __HIP_MEMORY_SCOPE_AGENT);
}

// --- 16B-bypass batched loads (8 ksteps = 16 dwordx4, stride 4096B) ---
struct B8 { bf16x8 h0,h1,h2,h3,h4,h5,h6,h7, l0,l1,l2,l3,l4,l5,l6,l7; };

__device__ __forceinline__ void issue8(const char* rb, B8& b) {
    const char* p0 = rb;
    const char* p1 = rb + 4096;
    const char* p2 = rb + 8192;
    const char* p3 = rb + 12288;
    const char* p4 = rb + 16384;
    const char* p5 = rb + 20480;
    const char* p6 = rb + 24576;
    const char* p7 = rb + 28672;
    asm volatile(
        "global_load_dwordx4 %0, %16, off sc0 sc1\n\t"
        "global_load_dwordx4 %8, %16, off offset:16 sc0 sc1\n\t"
        "global_load_dwordx4 %1, %17, off sc0 sc1\n\t"
        "global_load_dwordx4 %9, %17, off offset:16 sc0 sc1\n\t"
        "global_load_dwordx4 %2, %18, off sc0 sc1\n\t"
        "global_load_dwordx4 %10, %18, off offset:16 sc0 sc1\n\t"
        "global_load_dwordx4 %3, %19, off sc0 sc1\n\t"
        "global_load_dwordx4 %11, %19, off offset:16 sc0 sc1\n\t"
        "global_load_dwordx4 %4, %20, off sc0 sc1\n\t"
        "global_load_dwordx4 %12, %20, off offset:16 sc0 sc1\n\t"
        "global_load_dwordx4 %5, %21, off sc0 sc1\n\t"
        "global_load_dwordx4 %13, %21, off offset:16 sc0 sc1\n\t"
        "global_load_dwordx4 %6, %22, off sc0 sc1\n\t"
        "global_load_dwordx4 %14, %22, off offset:16 sc0 sc1\n\t"
        "global_load_dwordx4 %7, %23, off sc0 sc1\n\t"
        "global_load_dwordx4 %15, %23, off offset:16 sc0 sc1"
        : "=&v"(b.h0), "=&v"(b.h1), "=&v"(b.h2), "=&v"(b.h3),
          "=&v"(b.h4), "=&v"(b.h5), "=&v"(b.h6), "=&v"(b.h7),
          "=&v"(b.l0), "=&v"(b.l1), "=&v"(b.l2), "=&v"(b.l3),
          "=&v"(b.l4), "=&v"(b.l5), "=&v"(b.l6), "=&v"(b.l7)
        : "v"(p0), "v"(p1), "v"(p2), "v"(p3), "v"(p4), "v"(p5), "v"(p6), "v"(p7));
}

// Wait with all 16 staged values TIED through the asm: consumers must use the
// post-wait defs; sched_barrier stops MFMA hoisting (guide rule #18).
__device__ __forceinline__ void wait16(B8& b) {   // allow 16 outstanding (next batch)
    asm volatile("s_waitcnt vmcnt(16)"
        : "+v"(b.h0), "+v"(b.h1), "+v"(b.h2), "+v"(b.h3),
          "+v"(b.h4), "+v"(b.h5), "+v"(b.h6), "+v"(b.h7),
          "+v"(b.l0), "+v"(b.l1), "+v"(b.l2), "+v"(b.l3),
          "+v"(b.l4), "+v"(b.l5), "+v"(b.l6), "+v"(b.l7));
    __builtin_amdgcn_sched_barrier(0);
}
__device__ __forceinline__ void wait0(B8& b) {    // drain all
    asm volatile("s_waitcnt vmcnt(0)"
        : "+v"(b.h0), "+v"(b.h1), "+v"(b.h2), "+v"(b.h3),
          "+v"(b.h4), "+v"(b.h5), "+v"(b.h6), "+v"(b.h7),
          "+v"(b.l0), "+v"(b.l1), "+v"(b.l2), "+v"(b.l3),
          "+v"(b.l4), "+v"(b.l5), "+v"(b.l6), "+v"(b.l7));
    __builtin_amdgcn_sched_barrier(0);
}

#define MFMA_BF16 __builtin_amdgcn_mfma_f32_32x32x16_bf16

template<int S0>
__device__ __forceinline__ void consume8(const char* wa_h, const char* wa_l, const B8& b,
                                         f32x16& c0, f32x16& c1, f32x16& c2) {
#define KSTEP(J, BH, BL) { \
    bf16x8 ahi = *(const bf16x8*)(wa_h + (size_t)(S0 + J) * 2048); \
    bf16x8 alo = *(const bf16x8*)(wa_l + (size_t)(S0 + J) * 2048); \
    c0 = MFMA_BF16(ahi, BH, c0, 0, 0, 0); \
    c1 = MFMA_BF16(ahi, BL, c1, 0, 0, 0); \
    c2 = MFMA_BF16(alo, BH, c2, 0, 0, 0); }
    KSTEP(0, b.h0, b.l0) KSTEP(1, b.h1, b.l1) KSTEP(2, b.h2, b.l2) KSTEP(3, b.h3, b.l3)
    KSTEP(4, b.h4, b.l4) KSTEP(5, b.h5, b.l5) KSTEP(6, b.h6, b.l6) KSTEP(7, b.h7, b.l7)
#undef KSTEP
}

// 4-batch pipelined panel: ksteps [S0, S0+32) from rb (bypass), depth-2.
template<int S0>
__device__ __forceinline__ void panel32(const char* rb,
                                        const char* wa_h, const char* wa_l,
                                        f32x16& c0, f32x16& c1, f32x16& c2) {
    B8 A, B;
    issue8(rb, A);
    issue8(rb + 32768, B);
    wait16(A); consume8<S0>(wa_h, wa_l, A, c0, c1, c2);
    issue8(rb + 65536, A);
    wait16(B); consume8<S0 + 8>(wa_h, wa_l, B, c0, c1, c2);
    issue8(rb + 98304, B);
    wait16(A); consume8<S0 + 16>(wa_h, wa_l, A, c0, c1, c2);
    wait0(B);  consume8<S0 + 24>(wa_h, wa_l, B, c0, c1, c2);
}
// 2-batch version: ksteps [S0, S0+16) from rb.
template<int S0>
__device__ __forceinline__ void panel16(const char* rb,
                                        const char* wa_h, const char* wa_l,
                                        f32x16& c0, f32x16& c1, f32x16& c2) {
    B8 A, B;
    issue8(rb, A);
    issue8(rb + 32768, B);
    wait16(A); consume8<S0>(wa_h, wa_l, A, c0, c1, c2);
    wait0(B);  consume8<S0 + 8>(wa_h, wa_l, B, c0, c1, c2);
}

// Monitor block (one per layer): observe 64 arrivals >= g, fan out release.
__device__ void monitor_loop(unsigned* arr, unsigned* rel) {
    const int lane = threadIdx.x & 63;
    unsigned* a = arr + (size_t)lane * FLAG_STRIDE;
    unsigned* r = rel + (size_t)lane * FLAG_STRIDE;
    for (unsigned g = 1; g <= TT; ++g) {
        unsigned f = loadu_byp(a);
        while (__ballot(f < g) != 0ull) {
            __builtin_amdgcn_s_sleep(1);
            f = loadu_byp(a);
        }
        storeu_thru(r, g);
    }
}

template<int LAYER>
__device__ __forceinline__ void step_gate(const unsigned* rel_own, const unsigned* rel_prev,
                                          const unsigned* rel_next, int t) {
    const int lane = threadIdx.x & 63;
    const unsigned* addr = rel_own;
    unsigned tgt = (unsigned)t;
    if (LAYER > 0 && lane == 1) { addr = rel_prev; tgt = (unsigned)(t + 1); }
    if (LAYER < 2 && lane == 2) { addr = rel_next; tgt = (t >= 3) ? (unsigned)(t - 2) : 0u; }
    unsigned f = loadu_byp(addr);
    while (__ballot(f < tgt) != 0ull) {
        __builtin_amdgcn_s_sleep(1);
        f = loadu_byp(addr);
    }
}

// x [B,T,I] -> xTq [t][grp][b][hi 16B | lo 16B]
__global__ __launch_bounds__(256) void pack_x(const float* __restrict__ x,
                                              char* __restrict__ xTq) {
    const int t = blockIdx.x;
    const int b = threadIdx.x & 63;
    const int gq = threadIdx.x >> 6;
    #pragma unroll
    for (int gi = 0; gi < 2; ++gi) {
        const int g2 = gq + gi * 4;
        const float* src = x + ((size_t)b * TT + t) * II + g2 * 8;
        float w[8];
        *(float4*)&w[0] = *(const float4*)src;
        *(float4*)&w[4] = *(const float4*)(src + 4);
        bf16x8 hv, lv;
        #pragma unroll
        for (int j = 0; j < 8; ++j) {
            unsigned short h = f2bf(w[j]);
            hv[j] = (short)h;
            lv[j] = (short)f2bf(w[j] - bf2f(h));
        }
        char* dst = xTq + (((size_t)t * 8 + g2) * 64 + b) * 32;
        *(bf16x8*)dst = hv;
        *(bf16x8*)(dst + 16) = lv;
    }
}

// Pack 32 gate-rows into LDS in MFMA A-fragment order (swizzled layout).
template<int IN_DIM, int NKS>
__device__ void pack_weights(const float* __restrict__ Wih, const float* __restrict__ Whh,
                             int hbase, char* __restrict__ WAc) {
    const int lane = threadIdx.x & 63;
    const int wq = threadIdx.x >> 6;
    const int m = lane & 31;
    const int lg = lane >> 5;
    const int swz = (lane & 28) << 2;
    const int off_h = (lane * 32) ^ swz;
    const int off_l = (lane * 32 + 16) ^ swz;
    const int grow = (m >> 3) * HH + hbase + (m & 7);
    const float* wi = Wih + (size_t)grow * IN_DIM;
    const float* wh = Whh + (size_t)grow * HH;
    for (int s = wq; s < NKS; s += 4) {
        const int k8 = s * 16 + lg * 8;
        const float* src = (k8 < IN_DIM) ? (wi + k8) : (wh + (k8 - IN_DIM));
        float w[8];
        *(float4*)&w[0] = *(const float4*)src;
        *(float4*)&w[4] = *(const float4*)(src + 4);
        bf16x8 hv, lv;
        #pragma unroll
        for (int j = 0; j < 8; ++j) {
            unsigned short h = f2bf(w[j]);
            hv[j] = (short)h;
            lv[j] = (short)f2bf(w[j] - bf2f(h));
        }
        char* dst = WAc + (size_t)s * 2048;
        *(bf16x8*)(dst + off_h) = hv;
        *(bf16x8*)(dst + off_l) = lv;
    }
}

// hbuf_l: [parity][grp=64][b=64][hi16|lo16] — written by layer l, read by
// layers l (h-part) and l+1 (x-part, parity (t+1)&1). No x-copy buffers.
template<int LAYER, int IN_DIM, int NKS, int KH>
__device__ void lstm_core(int tile,
                          const char* __restrict__ xTq,
                          const char* __restrict__ hbuf_prev, char* __restrict__ hbuf,
                          float* __restrict__ h2last,
                          unsigned* __restrict__ arrive, unsigned* __restrict__ release,
                          const float* __restrict__ Wih, const float* __restrict__ Whh,
                          const float* __restrict__ bih, const float* __restrict__ bhh,
                          char* __restrict__ WAc, float* __restrict__ redbuf) {
    const int tid = threadIdx.x;
    const int lane = tid & 63;
    const int wq = tid >> 6;
    const int ntile = wq & 1;
    const int khalf = wq >> 1;
    const int lg = lane >> 5;
    const int b = ntile * 32 + (lane & 31);
    const int hbase = tile * 8;

    pack_weights<IN_DIM, NKS>(Wih, Whh, hbase, WAc);

    float bias_v[16];
    float cst[4] = {0.f, 0.f, 0.f, 0.f};
    if (khalf == 0) {
        #pragma unroll
        for (int g = 0; g < 4; ++g)
            #pragma unroll
            for (int j = 0; j < 4; ++j) {
                const int grow = g * HH + hbase + j + 4 * lg;
                bias_v[g * 4 + j] = bih[grow] + bhh[grow];
            }
    }
    __syncthreads();   // WA ready

    const int swz = (lane & 28) << 2;
    const char* wa_h = WAc + ((lane * 32) ^ swz);
    const char* wa_l = WAc + ((lane * 32 + 16) ^ swz);

    unsigned* const arr_own  = arrive + (size_t)(LAYER * 64 + tile) * FLAG_STRIDE;
    const unsigned* rel_own  = release + (size_t)(LAYER * 64 + tile) * FLAG_STRIDE;
    const unsigned* rel_prev = (LAYER > 0) ? release + (size_t)((LAYER - 1) * 64 + tile) * FLAG_STRIDE : rel_own;
    const unsigned* rel_next = (LAYER < 2) ? release + (size_t)((LAYER + 1) * 64 + tile) * FLAG_STRIDE : rel_own;
    const int xoff = lg * 2048 + b * 32;

    for (int t = 0; t < TT; ++t) {
        if (tid < 64) step_gate<LAYER>(rel_own, rel_prev, rel_next, t);
        __syncthreads();   // gate open for all waves

        f32x16 c0 = {0,0,0,0,0,0,0,0,0,0,0,0,0,0,0,0};
        f32x16 c1 = c0, c2 = c0;
        const char* rb_h = hbuf + (size_t)(t & 1) * 131072 + xoff;         // h(t-1)
        const char* rb_x = hbuf_prev + (size_t)((t + 1) & 1) * 131072 + xoff; // x(t)=h_{l-1}(t)

        if (khalf == 0) {
            if (LAYER == 0) {
                // x-part: 4 plain cached ksteps from xTq (read-only)
                const char* xq = xTq + (size_t)t * 16384 + xoff;
                #pragma unroll
                for (int s = 0; s < 4; ++s) {
                    bf16x8 bh = *(const bf16x8*)(xq + (size_t)s * 4096);
                    bf16x8 bl = *(const bf16x8*)(xq + (size_t)s * 4096 + 16);
                    bf16x8 ahi = *(const bf16x8*)(wa_h + (size_t)s * 2048);
                    bf16x8 alo = *(const bf16x8*)(wa_l + (size_t)s * 2048);
                    c0 = MFMA_BF16(ahi, bh, c0, 0, 0, 0);
                    c1 = MFMA_BF16(ahi, bl, c1, 0, 0, 0);
                    c2 = MFMA_BF16(alo, bh, c2, 0, 0, 0);
                }
                if (t > 0) panel16<4>(rb_h, wa_h, wa_l, c0, c1, c2);   // ring ksteps 4..19
            } else {
                panel32<0>(rb_x, wa_h, wa_l, c0, c1, c2);              // x ksteps 0..31
            }
        } else {
            if (LAYER == 0) {
                if (t > 0) panel16<20>(rb_h + 65536, wa_h, wa_l, c0, c1, c2); // ring 20..35
            } else {
                if (t > 0) panel32<32>(rb_h, wa_h, wa_l, c0, c1, c2);  // h ksteps 32..63
            }
        }

        f32x16 cs = c0 + c1 + c2;

        if (khalf == 1) {
            float* pw = &redbuf[((size_t)ntile * 64 + lane) * 20];
            #pragma unroll
            for (int q = 0; q < 4; ++q) {
                float4 v; v.x = cs[q*4+0]; v.y = cs[q*4+1]; v.z = cs[q*4+2]; v.w = cs[q*4+3];
                *(float4*)(pw + q * 4) = v;
            }
        }
        __syncthreads();
        if (khalf == 0) {
            const float* pr = &redbuf[((size_t)ntile * 64 + lane) * 20];
            float prv[16];
            #pragma unroll
            for (int q = 0; q < 4; ++q)
                *(float4*)&prv[q * 4] = *(const float4*)(pr + q * 4);
            float gate[16];
            #pragma unroll
            for (int r = 0; r < 16; ++r) gate[r] = cs[r] + prv[r] + bias_v[r];

            unsigned short his[4], los[4];
            #pragma unroll
            for (int j = 0; j < 4; ++j) {
                const float iv = sigmoidf_(gate[0 + j]);
                const float fv = sigmoidf_(gate[4 + j]);
                const float gv = tanhf(gate[8 + j]);
                const float ov = sigmoidf_(gate[12 + j]);
                cst[j] = fv * cst[j] + iv * gv;
                const float hv = ov * tanhf(cst[j]);
                his[j] = f2bf(hv);
                los[j] = f2bf(hv - bf2f(his[j]));
                if (LAYER == 2 && t == TT - 1)
                    storef_thru(h2last + (size_t)(hbase + j + 4 * lg) * 64 + b, hv);
            }
            unsigned long long hi2 = (unsigned long long)((unsigned)his[0] | ((unsigned)his[1] << 16))
                                   | ((unsigned long long)((unsigned)his[2] | ((unsigned)his[3] << 16)) << 32);
            unsigned long long lo2 = (unsigned long long)((unsigned)los[0] | ((unsigned)los[1] << 16))
                                   | ((unsigned long long)((unsigned)los[2] | ((unsigned)los[3] << 16)) << 32);

            // h(t) -> parity (t+1)&1; also serves as next layer's x(t)
            char* d2 = hbuf + (size_t)((t + 1) & 1) * 131072 + (size_t)tile * 2048 + b * 32 + lg * 8;
            store8_thru(d2, hi2);
            store8_thru(d2 + 16, lo2);
        }
        // publish: drain stores, then one arrive store
        __builtin_amdgcn_s_waitcnt(0);
        __syncthreads();
        if (tid == 0) storeu_thru(arr_own, (unsigned)(t + 1));
    }
}

__global__ __launch_bounds__(256, 1) void lstm_wavefront(
    const char* __restrict__ xTq,
    char* __restrict__ hbuf0, char* __restrict__ hbuf1, char* __restrict__ hbuf2,
    float* __restrict__ h2last,
    unsigned* __restrict__ arrive, unsigned* __restrict__ release,
    const float* __restrict__ Wih0, const float* __restrict__ Whh0,
    const float* __restrict__ bih0, const float* __restrict__ bhh0,
    const float* __restrict__ Wih1, const float* __restrict__ Whh1,
    const float* __restrict__ bih1, const float* __restrict__ bhh1,
    const float* __restrict__ Wih2, const float* __restrict__ Whh2,
    const float* __restrict__ bih2, const float* __restrict__ bhh2,
    const float* __restrict__ fcw, const float* __restrict__ fcb,
    float* __restrict__ out) {

    __shared__ short WA[64 * 64 * 16];     // 128 KB
    __shared__ float redbuf[2 * 64 * 20];  // 10 KB
    __shared__ float fcred[256];

    if (blockIdx.x >= NCOMP) {
        const int l = blockIdx.x - NCOMP;
        if (threadIdx.x < 64)
            monitor_loop(arrive + (size_t)l * 64 * FLAG_STRIDE,
                         release + (size_t)l * 64 * FLAG_STRIDE);
        return;
    }

    const int l = blockIdx.x >> 6;
    const int tile = blockIdx.x & 63;
    char* WAc = (char*)WA;

    if (l == 0)
        lstm_core<0, II, 36, 20>(tile, xTq, nullptr, hbuf0, h2last, arrive, release,
                                 Wih0, Whh0, bih0, bhh0, WAc, redbuf);
    else if (l == 1)
        lstm_core<1, HH, 64, 32>(tile, xTq, hbuf0, hbuf1, h2last, arrive, release,
                                 Wih1, Whh1, bih1, bhh1, WAc, redbuf);
    else
        lstm_core<2, HH, 64, 32>(tile, xTq, hbuf1, hbuf2, h2last, arrive, release,
                                 Wih2, Whh2, bih2, bhh2, WAc, redbuf);

    // final FC on h2[T-1]
    if (blockIdx.x == 0) {
        const unsigned* done = release + (size_t)(2 * 64) * FLAG_STRIDE;
        if (threadIdx.x < 64) {
            unsigned f = loadu_byp(done);
            while (__ballot(f < (unsigned)TT) != 0ull) {
                __builtin_amdgcn_s_sleep(1);
                f = loadu_byp(done);
            }
        }
        __syncthreads();
        const int tid = threadIdx.x;
        const int b = tid & 63, kq = tid >> 6;
        float s = 0.f;
        const float* hp = h2last + (size_t)kq * 128 * 64 + b;
        const float* wp = fcw + kq * 128;
        #pragma unroll 8
        for (int k = 0; k < 128; ++k)
            s = fmaf(loadf_byp(hp + (size_t)k * 64), wp[k], s);
        fcred[tid] = s;
        __syncthreads();
        if (tid < 64)
            out[tid] = fcred[tid] + fcred[64 + tid] + fcred[128 + tid] + fcred[192 + tid] + fcb[0];
    }
}

extern "C" void kernel_launch(void* const* d_in, const int* in_sizes, int n_in,
                              void* d_out, int out_size, void* d_ws, size_t ws_size,
                              hipStream_t stream) {
    (void)in_sizes; (void)n_in; (void)out_size; (void)ws_size;

    const float* x    = (const float*)d_in[0];
    const float* Wih0 = (const float*)d_in[1];
    const float* Whh0 = (const float*)d_in[2];
    const float* bih0 = (const float*)d_in[3];
    const float* bhh0 = (const float*)d_in[4];
    const float* Wih1 = (const float*)d_in[5];
    const float* Whh1 = (const float*)d_in[6];
    const float* bih1 = (const float*)d_in[7];
    const float* bhh1 = (const float*)d_in[8];
    const float* Wih2 = (const float*)d_in[9];
    const float* Whh2 = (const float*)d_in[10];
    const float* bih2 = (const float*)d_in[11];
    const float* bhh2 = (const float*)d_in[12];
    const float* fcw  = (const float*)d_in[13];
    const float* fcb  = (const float*)d_in[14];

    char* ws = (char*)d_ws;
    unsigned* arrive  = (unsigned*)ws;                     // 24 KB
    unsigned* release = (unsigned*)(ws + 24576);           // 24 KB
    char* hbuf0   = ws + 65536;                            // 2*64*64*32 = 256 KB each
    char* hbuf1   = hbuf0 + 2 * 64 * 64 * 32;
    char* hbuf2   = hbuf1 + 2 * 64 * 64 * 32;
    float* h2last = (float*)(hbuf2 + 2 * 64 * 64 * 32);    // 128 KB
    char* xTq     = (char*)h2last + 512 * 64 * 4;          // 8 MB

    hipMemsetAsync(ws, 0, 65536, stream);

    pack_x<<<TT, 256, 0, stream>>>(x, xTq);

    lstm_wavefront<<<NBLK, 256, 0, stream>>>(
        xTq, hbuf0, hbuf1, hbuf2, h2last, arrive, release,
        Wih0, Whh0, bih0, bhh0,
        Wih1, Whh1, bih1, bhh1,
        Wih2, Whh2, bih2, bhh2,
        fcw, fcb, (float*)d_out);
}